// Round 11
// baseline (233.301 us; speedup 1.0000x reference)
//
#include <hip/hip_runtime.h>
#include <math.h>

#define H_SIZE   4096
#define N_HEADS  32
#define N_KV     8
#define HEAD_DIM 128
#define GROUP    4
#define Q_SIZE   4096
#define KV_SIZE  1024
#define QKV_OUT  6144          // Q_SIZE + 2*KV_SIZE
#define NUM_SEQS 64
#define MAX_CTX  2048
#define BLK_SZ   16
#define BLOCKS_PER_SEQ 128
#define ATT_SCALE 0.08838834764831845f   // 128^-0.5

#define CHUNK    128           // tokens per attn workgroup (4 waves x 32)
#define NCHUNK   16            // MAX_CTX / CHUNK
#define KSPLIT   8
#define KCHUNK   512           // H_SIZE / KSPLIT

typedef __attribute__((ext_vector_type(8))) short bf16x8;
typedef __attribute__((ext_vector_type(4))) float f32x4;

__device__ __forceinline__ short f2bf(float f) {
    return __builtin_bit_cast(short, (__bf16)f);   // lowers to v_cvt_pk_bf16_f32
}

__device__ __forceinline__ bf16x8 cvt8(float4 a, float4 b) {
    bf16x8 r;
    r[0]=f2bf(a.x); r[1]=f2bf(a.y); r[2]=f2bf(a.z); r[3]=f2bf(a.w);
    r[4]=f2bf(b.x); r[5]=f2bf(b.y); r[6]=f2bf(b.z); r[7]=f2bf(b.w);
    return r;
}

// ---------------- fp32 -> bf16 bulk convert (X operand, done once) ----------------
__global__ __launch_bounds__(256)
void cvt_bf16(const float* __restrict__ in, unsigned short* __restrict__ out, int n4) {
    int i = blockIdx.x * 256 + threadIdx.x;
    if (i >= n4) return;
    float4 v = *(const float4*)(in + (size_t)i * 4);
    ushort2 lo = { (unsigned short)f2bf(v.x), (unsigned short)f2bf(v.y) };
    ushort2 hi = { (unsigned short)f2bf(v.z), (unsigned short)f2bf(v.w) };
    *(ushort2*)(out + (size_t)i * 4)     = lo;
    *(ushort2*)(out + (size_t)i * 4 + 2) = hi;
}

// ---------------- MFMA GEMM: Yp[c][64][N] = A[64][4096] @ W[N][4096]^T ----------
__global__ __launch_bounds__(256)
void gemm_mfma(const unsigned short* __restrict__ A, const float* __restrict__ W,
               float* __restrict__ Yp, int N) {
    const int n0   = blockIdx.x * 64;
    const int k0   = blockIdx.y * KCHUNK;
    const int wave = threadIdx.x >> 6;
    const int lane = threadIdx.x & 63;
    const int ncol = n0 + wave * 16 + (lane & 15);
    const int klane = (lane >> 4) * 8;

    const float*          wrow = W + (size_t)ncol * H_SIZE + k0 + klane;
    const unsigned short* arow = A + (size_t)(lane & 15) * H_SIZE + k0 + klane;

    f32x4 acc[4] = {};
    for (int k = 0; k < KCHUNK; k += 32) {
        float4 wa = *(const float4*)(wrow + k);
        float4 wb = *(const float4*)(wrow + k + 4);
        bf16x8 bf = cvt8(wa, wb);
        #pragma unroll
        for (int m = 0; m < 4; ++m) {
            bf16x8 af = *(const bf16x8*)(const void*)(arow + (size_t)m * 16 * H_SIZE + k);
            acc[m] = __builtin_amdgcn_mfma_f32_16x16x32_bf16(af, bf, acc[m], 0, 0, 0);
        }
    }
    float* yp = Yp + (size_t)blockIdx.y * 64 * N;
    #pragma unroll
    for (int m = 0; m < 4; ++m)
        #pragma unroll
        for (int j = 0; j < 4; ++j)
            yp[(size_t)(m * 16 + (lane >> 4) * 4 + j) * N + ncol] = acc[m][j];
}

// ---------------- fused K-split reduce + RoPE for QKV ----------------
__global__ __launch_bounds__(256)
void qkv_reduce_rope(const float* __restrict__ Yp, float* __restrict__ qkv,
                     const int* __restrict__ positions) {
    const int s   = blockIdx.x;
    const int idx = blockIdx.y * 256 + threadIdx.x;
    const float pos = (float)positions[s];
    if (idx < 2560) {
        const int head = idx >> 6, d = idx & 63;
        const int j1 = (head < N_HEADS ? head * HEAD_DIM
                                       : Q_SIZE + (head - N_HEADS) * HEAD_DIM) + d;
        const int j2 = j1 + 64;
        float x1 = 0.f, x2 = 0.f;
        #pragma unroll
        for (int c = 0; c < KSPLIT; ++c) {
            x1 += Yp[((size_t)c * 64 + s) * QKV_OUT + j1];
            x2 += Yp[((size_t)c * 64 + s) * QKV_OUT + j2];
        }
        const float inv_freq = powf(10000.0f, -(float)d / 64.0f);
        const float ang = pos * inv_freq;
        const float cs = cosf(ang), sn = sinf(ang);
        qkv[(size_t)s * QKV_OUT + j1] = x1 * cs - x2 * sn;
        qkv[(size_t)s * QKV_OUT + j2] = x2 * cs + x1 * sn;
    } else if (idx < 3584) {
        const int j = Q_SIZE + KV_SIZE + (idx - 2560);
        float v = 0.f;
        #pragma unroll
        for (int c = 0; c < KSPLIT; ++c)
            v += Yp[((size_t)c * 64 + s) * QKV_OUT + j];
        qkv[(size_t)s * QKV_OUT + j] = v;
    }
}

__global__ __launch_bounds__(256)
void reduce_ksplit(const float* __restrict__ Yp, float* __restrict__ Y, int total) {
    int i = blockIdx.x * 256 + threadIdx.x;
    if (i >= total) return;
    float s = 0.f;
    #pragma unroll
    for (int c = 0; c < KSPLIT; ++c) s += Yp[(size_t)c * total + i];
    Y[i] = s;
}

// ---------------- Flash-decode attention: wave-independent, 2 barriers ----------------
// grid (NUM_SEQS*N_KV, NCHUNK); block 256 = 4 waves; chunk = 128 tokens.
// Each wave: K loads -> in-register softmax (shuffles only) -> PV (p via shfl bcast).
// Cross-wave: one weighted exp(m_w - M) combine at the end.
__global__ __launch_bounds__(256)
void attn_chunk(const float* __restrict__ qkv,
                const float* __restrict__ k_cache,
                const float* __restrict__ v_cache,
                const int*   __restrict__ block_tables,
                const int*   __restrict__ context_lens,
                float* __restrict__ pacc,   // [sh][c][g][128]
                float* __restrict__ pml) {  // [sh][c][g][2]
    const int sh = blockIdx.x;
    const int s  = sh >> 3;
    const int h  = sh & 7;
    const int c  = blockIdx.y;
    const int ctx = context_lens[s];
    if (c * CHUNK >= ctx) return;
    const int pos = ctx - 1;
    const int nv = min(CHUNK, ctx - c * CHUNK);

    __shared__ float qs[GROUP][HEAD_DIM];     // 2 KB
    __shared__ float red[4][GROUP][HEAD_DIM]; // 8 KB
    __shared__ float mw[4][GROUP];            // wave-local max
    __shared__ float lw[4][GROUP];            // wave-local sum

    const int tid  = threadIdx.x;
    const int w    = tid >> 6;
    const int lane = tid & 63;

    {   // q for this group's 4 heads: 512 contiguous floats, 256 thr x float2
        int i = tid * 2;
        const float* qsrc = qkv + (size_t)s * QKV_OUT + h * (GROUP * HEAD_DIM);
        *(float2*)(&qs[i >> 7][i & 127]) = *(const float2*)(qsrc + i);
    }
    __syncthreads();

    const int*   bt   = block_tables + s * BLOCKS_PER_SEQ;
    const float* ksec = qkv + (size_t)s * QKV_OUT + Q_SIZE + h * HEAD_DIM;
    const float* vsec = qkv + (size_t)s * QKV_OUT + Q_SIZE + KV_SIZE + h * HEAD_DIM;

    // this wave's two cache blocks (tokens w*32..+15 and +16..+31)
    const int blk0 = bt[c * (CHUNK / BLK_SZ) + w * 2];
    const int blk1 = bt[c * (CHUNK / BLK_SZ) + w * 2 + 1];

    // ---- K phase: token tk = w*32 + lane/2; lane&1 picks 64-dim half-row ----
    float p0, p1, p2, p3;           // this lane's token's probs (4 heads)
    {
        const int tk   = w * 32 + (lane >> 1);
        const int half = lane & 1;
        const int T    = c * CHUNK + tk;
        const int blk  = (lane < 32) ? blk0 : blk1;
        const float* kp = (T == pos) ? ksec
            : k_cache + ((size_t)(blk * BLK_SZ + (tk & 15)) * N_KV + h) * HEAD_DIM;
        kp += half * 64;
        const float* q0 = &qs[0][half * 64];
        const float* q1 = &qs[1][half * 64];
        const float* q2 = &qs[2][half * 64];
        const float* q3 = &qs[3][half * 64];
        float d0 = 0.f, d1 = 0.f, d2 = 0.f, d3 = 0.f;
        #pragma unroll
        for (int b = 0; b < 2; ++b) {
            float4 kv[8];
            #pragma unroll
            for (int j = 0; j < 8; ++j) kv[j] = *(const float4*)(kp + b * 32 + j * 4);
            #pragma unroll
            for (int j = 0; j < 8; ++j) {
                const float4 A = kv[j];
                const float4 x0 = *(const float4*)(q0 + b * 32 + j * 4);
                const float4 x1 = *(const float4*)(q1 + b * 32 + j * 4);
                const float4 x2 = *(const float4*)(q2 + b * 32 + j * 4);
                const float4 x3 = *(const float4*)(q3 + b * 32 + j * 4);
                d0 = fmaf(A.x,x0.x, fmaf(A.y,x0.y, fmaf(A.z,x0.z, fmaf(A.w,x0.w, d0))));
                d1 = fmaf(A.x,x1.x, fmaf(A.y,x1.y, fmaf(A.z,x1.z, fmaf(A.w,x1.w, d1))));
                d2 = fmaf(A.x,x2.x, fmaf(A.y,x2.y, fmaf(A.z,x2.z, fmaf(A.w,x2.w, d2))));
                d3 = fmaf(A.x,x3.x, fmaf(A.y,x3.y, fmaf(A.z,x3.z, fmaf(A.w,x3.w, d3))));
            }
        }
        d0 += __shfl_xor(d0, 1);
        d1 += __shfl_xor(d1, 1);
        d2 += __shfl_xor(d2, 1);
        d3 += __shfl_xor(d3, 1);
        // mask invalid tokens, scale
        const bool vmask = (tk < nv);
        float s0 = vmask ? d0 * ATT_SCALE : -1e30f;
        float s1 = vmask ? d1 * ATT_SCALE : -1e30f;
        float s2 = vmask ? d2 * ATT_SCALE : -1e30f;
        float s3 = vmask ? d3 * ATT_SCALE : -1e30f;
        // wave-local max over the 32 distinct tokens. After the pair-reduce, token t
        // lives (duplicated) in lanes 2t/2t+1; the stride-{2..32} butterfly reduces
        // over the 32 same-parity lanes = each token EXACTLY ONCE (no duplication).
        float m0 = s0, m1 = s1, m2 = s2, m3 = s3;
        #pragma unroll
        for (int off = 2; off <= 32; off <<= 1) {
            m0 = fmaxf(m0, __shfl_xor(m0, off));
            m1 = fmaxf(m1, __shfl_xor(m1, off));
            m2 = fmaxf(m2, __shfl_xor(m2, off));
            m3 = fmaxf(m3, __shfl_xor(m3, off));
        }
        p0 = __expf(s0 - m0);
        p1 = __expf(s1 - m1);
        p2 = __expf(s2 - m2);
        p3 = __expf(s3 - m3);
        float l0 = p0, l1 = p1, l2 = p2, l3 = p3;
        #pragma unroll
        for (int off = 2; off <= 32; off <<= 1) {
            l0 += __shfl_xor(l0, off);
            l1 += __shfl_xor(l1, off);
            l2 += __shfl_xor(l2, off);
            l3 += __shfl_xor(l3, off);
        }
        if (lane == 0) {
            mw[w][0] = m0; mw[w][1] = m1; mw[w][2] = m2; mw[w][3] = m3;
            lw[w][0] = l0; lw[w][1] = l1;   // NO halving: butterfly counts each token once
            lw[w][2] = l2; lw[w][3] = l3;
        }
    }

    // ---- PV (no barrier needed: uses this wave's own p via shuffles) ----
    {
        const int t0 = w * 32;
        const float* vb0 = v_cache + (size_t)blk0 * (BLK_SZ * N_KV * HEAD_DIM)
                         + (size_t)h * HEAD_DIM + lane * 2;
        const float* vb1 = v_cache + (size_t)blk1 * (BLK_SZ * N_KV * HEAD_DIM)
                         + (size_t)h * HEAD_DIM + lane * 2;
        const float* vnewp = vsec + lane * 2;
        float2 a0 = {0,0}, a1 = {0,0}, a2 = {0,0}, a3 = {0,0};
        #pragma unroll
        for (int tb = 0; tb < 32; tb += 8) {
            float2 vv[8];
            #pragma unroll
            for (int u = 0; u < 8; ++u) {
                const int tt = tb + u;                     // 0..31 compile-time
                const float* vp = (c * CHUNK + t0 + tt == pos) ? vnewp
                    : ((tt < 16 ? vb0 : vb1) + (size_t)(tt & 15) * (N_KV * HEAD_DIM));
                vv[u] = *(const float2*)vp;
            }
            #pragma unroll
            for (int u = 0; u < 8; ++u) {
                const int tt = tb + u;
                const float q0 = __shfl(p0, 2 * tt);
                const float q1 = __shfl(p1, 2 * tt);
                const float q2 = __shfl(p2, 2 * tt);
                const float q3 = __shfl(p3, 2 * tt);
                a0.x = fmaf(q0, vv[u].x, a0.x); a0.y = fmaf(q0, vv[u].y, a0.y);
                a1.x = fmaf(q1, vv[u].x, a1.x); a1.y = fmaf(q1, vv[u].y, a1.y);
                a2.x = fmaf(q2, vv[u].x, a2.x); a2.y = fmaf(q2, vv[u].y, a2.y);
                a3.x = fmaf(q3, vv[u].x, a3.x); a3.y = fmaf(q3, vv[u].y, a3.y);
            }
        }
        *(float2*)(&red[w][0][lane * 2]) = a0;
        *(float2*)(&red[w][1][lane * 2]) = a1;
        *(float2*)(&red[w][2][lane * 2]) = a2;
        *(float2*)(&red[w][3][lane * 2]) = a3;
    }
    __syncthreads();

    {   // weighted cross-wave combine: 256 thr x float2 = 4 heads x 128 dims
        const int g = tid >> 6, d = (tid & 63) * 2;
        const float m0 = mw[0][g], m1 = mw[1][g], m2 = mw[2][g], m3 = mw[3][g];
        float M = fmaxf(fmaxf(m0, m1), fmaxf(m2, m3));
        const float e0 = __expf(m0 - M), e1 = __expf(m1 - M);
        const float e2 = __expf(m2 - M), e3 = __expf(m3 - M);
        float ox = red[0][g][d]   * e0 + red[1][g][d]   * e1
                 + red[2][g][d]   * e2 + red[3][g][d]   * e3;
        float oy = red[0][g][d+1] * e0 + red[1][g][d+1] * e1
                 + red[2][g][d+1] * e2 + red[3][g][d+1] * e3;
        size_t ob = (((size_t)sh * NCHUNK + c) * GROUP + g) * HEAD_DIM + d;
        *(float2*)(pacc + ob) = make_float2(ox, oy);
        if ((tid & 63) == 0) {
            const float L = lw[0][g] * e0 + lw[1][g] * e1 + lw[2][g] * e2 + lw[3][g] * e3;
            size_t ib = (((size_t)sh * NCHUNK + c) * GROUP + g) * 2;
            pml[ib] = M; pml[ib + 1] = L;
        }
    }
}

// ---------------- combine chunk partials; emit bf16 for the O-GEMM ----------------
__global__ __launch_bounds__(256)
void attn_reduce(const float* __restrict__ pacc, const float* __restrict__ pml,
                 const int* __restrict__ context_lens, unsigned short* __restrict__ outbf) {
    const int sh = blockIdx.x;
    const int s  = sh >> 3;
    const int h  = sh & 7;
    const int g    = threadIdx.x >> 6;
    const int lane = threadIdx.x & 63;
    const int ctx = context_lens[s];
    const int nc  = (ctx + CHUNK - 1) / CHUNK;

    float M = -1e30f;
    for (int cc = 0; cc < nc; ++cc)
        M = fmaxf(M, pml[(((size_t)sh * NCHUNK + cc) * GROUP + g) * 2]);
    float ox = 0.f, oy = 0.f, L = 0.f;
    for (int cc = 0; cc < nc; ++cc) {
        size_t idx = ((size_t)sh * NCHUNK + cc) * GROUP + g;
        float w = __expf(pml[idx*2] - M);
        L = fmaf(w, pml[idx*2+1], L);
        float2 pa = *(const float2*)(pacc + idx * HEAD_DIM + lane*2);
        ox = fmaf(w, pa.x, ox);
        oy = fmaf(w, pa.y, oy);
    }
    float inv = 1.0f / L;
    unsigned short* op = outbf + (size_t)s * Q_SIZE + (h * GROUP + g) * HEAD_DIM;
    ushort2 o2 = { (unsigned short)f2bf(ox * inv), (unsigned short)f2bf(oy * inv) };
    *(ushort2*)(op + lane * 2) = o2;
}

extern "C" void kernel_launch(void* const* d_in, const int* in_sizes, int n_in,
                              void* d_out, int out_size, void* d_ws, size_t ws_size,
                              hipStream_t stream) {
    const int*   positions    = (const int*)  d_in[0];
    const float* hidden       = (const float*)d_in[1];
    const float* k_cache      = (const float*)d_in[2];
    const float* v_cache      = (const float*)d_in[3];
    const int*   block_tables = (const int*)  d_in[4];
    const int*   context_lens = (const int*)  d_in[5];
    const float* W_qkv        = (const float*)d_in[6];
    const float* W_o          = (const float*)d_in[7];
    float* out = (float*)d_out;

    float* qkv_ws = (float*)d_ws;                                     // 393216 f
    unsigned short* hidden_bf = (unsigned short*)(qkv_ws + (size_t)NUM_SEQS * QKV_OUT);
    unsigned short* attn_bf   = hidden_bf + (size_t)NUM_SEQS * H_SIZE;
    float* scratch = (float*)(attn_bf + (size_t)NUM_SEQS * H_SIZE);    // reused region
    // scratch reuse: QKV partials (3.1M f) -> attn pacc/pml (4.3M f) -> O partials (2.1M f)
    float* pacc = scratch;                                             // 512*16*4*128 f
    float* pml  = scratch + (size_t)NUM_SEQS * N_KV * NCHUNK * GROUP * HEAD_DIM;

    // 0) X -> bf16 (once)
    cvt_bf16<<<(NUM_SEQS * H_SIZE / 4 + 255) / 256, 256, 0, stream>>>(
        hidden, hidden_bf, NUM_SEQS * H_SIZE / 4);
    // 1) QKV projection + fused reduce+RoPE
    gemm_mfma<<<dim3(QKV_OUT / 64, KSPLIT), 256, 0, stream>>>(hidden_bf, W_qkv, scratch, QKV_OUT);
    qkv_reduce_rope<<<dim3(NUM_SEQS, 14), 256, 0, stream>>>(scratch, qkv_ws, positions);
    // 2) flash-decode attention + combine
    attn_chunk<<<dim3(NUM_SEQS * N_KV, NCHUNK), 256, 0, stream>>>(
        qkv_ws, k_cache, v_cache, block_tables, context_lens, pacc, pml);
    attn_reduce<<<NUM_SEQS * N_KV, 256, 0, stream>>>(pacc, pml, context_lens, attn_bf);
    // 3) output projection + reduce
    gemm_mfma<<<dim3(Q_SIZE / 64, KSPLIT), 256, 0, stream>>>(attn_bf, W_o, scratch, Q_SIZE);
    reduce_ksplit<<<(NUM_SEQS * Q_SIZE + 255) / 256, 256, 0, stream>>>(scratch, out, NUM_SEQS * Q_SIZE);
}

// Round 12
// 197.658 us; speedup vs baseline: 1.1803x; 1.1803x over previous
//
#include <hip/hip_runtime.h>
#include <math.h>

#define H_SIZE   4096
#define N_HEADS  32
#define N_KV     8
#define HEAD_DIM 128
#define GROUP    4
#define Q_SIZE   4096
#define KV_SIZE  1024
#define QKV_OUT  6144          // Q_SIZE + 2*KV_SIZE
#define NUM_SEQS 64
#define MAX_CTX  2048
#define BLK_SZ   16
#define BLOCKS_PER_SEQ 128
#define ATT_SCALE 0.08838834764831845f   // 128^-0.5

#define CHUNK    128           // tokens per attn workgroup (4 waves x 32)
#define NCHUNK   16            // MAX_CTX / CHUNK
#define KSPLIT   8
#define KCHUNK   512           // H_SIZE / KSPLIT

typedef __attribute__((ext_vector_type(8))) short bf16x8;
typedef __attribute__((ext_vector_type(4))) float f32x4;

__device__ __forceinline__ short f2bf(float f) {
    return __builtin_bit_cast(short, (__bf16)f);   // lowers to v_cvt_pk_bf16_f32
}

__device__ __forceinline__ bf16x8 cvt8(float4 a, float4 b) {
    bf16x8 r;
    r[0]=f2bf(a.x); r[1]=f2bf(a.y); r[2]=f2bf(a.z); r[3]=f2bf(a.w);
    r[4]=f2bf(b.x); r[5]=f2bf(b.y); r[6]=f2bf(b.z); r[7]=f2bf(b.w);
    return r;
}

// ---------------- fp32 -> bf16 bulk convert (X operand, done once) ----------------
__global__ __launch_bounds__(256)
void cvt_bf16(const float* __restrict__ in, unsigned short* __restrict__ out, int n4) {
    int i = blockIdx.x * 256 + threadIdx.x;
    if (i >= n4) return;
    float4 v = *(const float4*)(in + (size_t)i * 4);
    ushort2 lo = { (unsigned short)f2bf(v.x), (unsigned short)f2bf(v.y) };
    ushort2 hi = { (unsigned short)f2bf(v.z), (unsigned short)f2bf(v.w) };
    *(ushort2*)(out + (size_t)i * 4)     = lo;
    *(ushort2*)(out + (size_t)i * 4 + 2) = hi;
}

// ---------------- MFMA GEMM: Yp[c][64][N] = A[64][4096] @ W[N][4096]^T ----------
__global__ __launch_bounds__(256)
void gemm_mfma(const unsigned short* __restrict__ A, const float* __restrict__ W,
               float* __restrict__ Yp, int N) {
    const int n0   = blockIdx.x * 64;
    const int k0   = blockIdx.y * KCHUNK;
    const int wave = threadIdx.x >> 6;
    const int lane = threadIdx.x & 63;
    const int ncol = n0 + wave * 16 + (lane & 15);
    const int klane = (lane >> 4) * 8;

    const float*          wrow = W + (size_t)ncol * H_SIZE + k0 + klane;
    const unsigned short* arow = A + (size_t)(lane & 15) * H_SIZE + k0 + klane;

    f32x4 acc[4] = {};
    for (int k = 0; k < KCHUNK; k += 32) {
        float4 wa = *(const float4*)(wrow + k);
        float4 wb = *(const float4*)(wrow + k + 4);
        bf16x8 bf = cvt8(wa, wb);
        #pragma unroll
        for (int m = 0; m < 4; ++m) {
            bf16x8 af = *(const bf16x8*)(const void*)(arow + (size_t)m * 16 * H_SIZE + k);
            acc[m] = __builtin_amdgcn_mfma_f32_16x16x32_bf16(af, bf, acc[m], 0, 0, 0);
        }
    }
    float* yp = Yp + (size_t)blockIdx.y * 64 * N;
    #pragma unroll
    for (int m = 0; m < 4; ++m)
        #pragma unroll
        for (int j = 0; j < 4; ++j)
            yp[(size_t)(m * 16 + (lane >> 4) * 4 + j) * N + ncol] = acc[m][j];
}

// ---------------- fused K-split reduce + RoPE for QKV ----------------
__global__ __launch_bounds__(256)
void qkv_reduce_rope(const float* __restrict__ Yp, float* __restrict__ qkv,
                     const int* __restrict__ positions) {
    const int s   = blockIdx.x;
    const int idx = blockIdx.y * 256 + threadIdx.x;
    const float pos = (float)positions[s];
    if (idx < 2560) {
        const int head = idx >> 6, d = idx & 63;
        const int j1 = (head < N_HEADS ? head * HEAD_DIM
                                       : Q_SIZE + (head - N_HEADS) * HEAD_DIM) + d;
        const int j2 = j1 + 64;
        float x1 = 0.f, x2 = 0.f;
        #pragma unroll
        for (int c = 0; c < KSPLIT; ++c) {
            x1 += Yp[((size_t)c * 64 + s) * QKV_OUT + j1];
            x2 += Yp[((size_t)c * 64 + s) * QKV_OUT + j2];
        }
        const float inv_freq = powf(10000.0f, -(float)d / 64.0f);
        const float ang = pos * inv_freq;
        const float cs = cosf(ang), sn = sinf(ang);
        qkv[(size_t)s * QKV_OUT + j1] = x1 * cs - x2 * sn;
        qkv[(size_t)s * QKV_OUT + j2] = x2 * cs + x1 * sn;
    } else if (idx < 3584) {
        const int j = Q_SIZE + KV_SIZE + (idx - 2560);
        float v = 0.f;
        #pragma unroll
        for (int c = 0; c < KSPLIT; ++c)
            v += Yp[((size_t)c * 64 + s) * QKV_OUT + j];
        qkv[(size_t)s * QKV_OUT + j] = v;
    }
}

__global__ __launch_bounds__(256)
void reduce_ksplit(const float* __restrict__ Yp, float* __restrict__ Y, int total) {
    int i = blockIdx.x * 256 + threadIdx.x;
    if (i >= total) return;
    float s = 0.f;
    #pragma unroll
    for (int c = 0; c < KSPLIT; ++c) s += Yp[(size_t)c * total + i];
    Y[i] = s;
}

// ---------------- Flash-decode attention: line-clean K loads (oct scheme) ----------------
// grid (NUM_SEQS*N_KV, NCHUNK); block 256 = 4 waves; chunk = 128 tokens.
// K phase: lane = (token j8 = lane>>3, oct = lane&7). Each load instruction touches
// 8 rows x one 128B line, fully consumed by the 8 octs IN THAT INSTRUCTION (no L1
// residency requirement). Dot-reduce over octs via 3-stage shfl; softmax via 4 slots
// + 3-stage butterfly; PV unchanged (float2 rows are already line-clean).
__global__ __launch_bounds__(256)
void attn_chunk(const float* __restrict__ qkv,
                const float* __restrict__ k_cache,
                const float* __restrict__ v_cache,
                const int*   __restrict__ block_tables,
                const int*   __restrict__ context_lens,
                float* __restrict__ pacc,   // [sh][c][g][128]
                float* __restrict__ pml) {  // [sh][c][g][2]
    const int sh = blockIdx.x;
    const int s  = sh >> 3;
    const int h  = sh & 7;
    const int c  = blockIdx.y;
    const int ctx = context_lens[s];
    if (c * CHUNK >= ctx) return;
    const int pos = ctx - 1;
    const int nv = min(CHUNK, ctx - c * CHUNK);

    __shared__ float qs[GROUP][HEAD_DIM];     // 2 KB
    __shared__ float red[4][GROUP][HEAD_DIM]; // 8 KB
    __shared__ float mw[4][GROUP];            // wave-local max
    __shared__ float lw[4][GROUP];            // wave-local sum

    const int tid  = threadIdx.x;
    const int w    = tid >> 6;
    const int lane = tid & 63;

    {   // q for this group's 4 heads: 512 contiguous floats, 256 thr x float2
        int i = tid * 2;
        const float* qsrc = qkv + (size_t)s * QKV_OUT + h * (GROUP * HEAD_DIM);
        *(float2*)(&qs[i >> 7][i & 127]) = *(const float2*)(qsrc + i);
    }
    __syncthreads();

    const int*   bt   = block_tables + s * BLOCKS_PER_SEQ;
    const float* ksec = qkv + (size_t)s * QKV_OUT + Q_SIZE + h * HEAD_DIM;
    const float* vsec = qkv + (size_t)s * QKV_OUT + Q_SIZE + KV_SIZE + h * HEAD_DIM;

    // this wave's two cache blocks (tokens w*32..+15 and +16..+31)
    const int blk0 = bt[c * (CHUNK / BLK_SZ) + w * 2];
    const int blk1 = bt[c * (CHUNK / BLK_SZ) + w * 2 + 1];

    // ---- K phase: 4 token-groups of 8; lane = (j8 = lane>>3 token, oct = lane&7) ----
    float ps0[4], ps1[4], ps2[4], ps3[4];   // prob slots: token tg*8 + (lane>>3)
    {
        const int j8  = lane >> 3;
        const int oct = lane & 7;
        float sl0[4], sl1[4], sl2[4], sl3[4];
        #pragma unroll
        for (int tg = 0; tg < 4; ++tg) {
            const int tk = tg * 8 + j8;            // token in wave 0..31
            const int T  = c * CHUNK + w * 32 + tk;
            const int blk = (tk < 16) ? blk0 : blk1;
            const float* kp = (T == pos) ? ksec
                : k_cache + ((size_t)(blk * BLK_SZ + (tk & 15)) * N_KV + h) * HEAD_DIM;
            float d0 = 0.f, d1 = 0.f, d2 = 0.f, d3 = 0.f;
            #pragma unroll
            for (int i = 0; i < 4; ++i) {
                const int o = i * 32 + oct * 4;    // float offset; 16B chunk
                float4 kv = *(const float4*)(kp + o);
                float4 x0 = *(const float4*)(&qs[0][o]);
                float4 x1 = *(const float4*)(&qs[1][o]);
                float4 x2 = *(const float4*)(&qs[2][o]);
                float4 x3 = *(const float4*)(&qs[3][o]);
                d0 = fmaf(kv.x,x0.x, fmaf(kv.y,x0.y, fmaf(kv.z,x0.z, fmaf(kv.w,x0.w, d0))));
                d1 = fmaf(kv.x,x1.x, fmaf(kv.y,x1.y, fmaf(kv.z,x1.z, fmaf(kv.w,x1.w, d1))));
                d2 = fmaf(kv.x,x2.x, fmaf(kv.y,x2.y, fmaf(kv.z,x2.z, fmaf(kv.w,x2.w, d2))));
                d3 = fmaf(kv.x,x3.x, fmaf(kv.y,x3.y, fmaf(kv.z,x3.z, fmaf(kv.w,x3.w, d3))));
            }
            // reduce over the 8 octs (strides 1,2,4)
            #pragma unroll
            for (int off = 1; off <= 4; off <<= 1) {
                d0 += __shfl_xor(d0, off);
                d1 += __shfl_xor(d1, off);
                d2 += __shfl_xor(d2, off);
                d3 += __shfl_xor(d3, off);
            }
            const bool vmask = (w * 32 + tk) < nv;
            sl0[tg] = vmask ? d0 * ATT_SCALE : -1e30f;
            sl1[tg] = vmask ? d1 * ATT_SCALE : -1e30f;
            sl2[tg] = vmask ? d2 * ATT_SCALE : -1e30f;
            sl3[tg] = vmask ? d3 * ATT_SCALE : -1e30f;
        }
        // wave max per head: 4 local slots + butterfly over strides 8,16,32
        float m0 = fmaxf(fmaxf(sl0[0], sl0[1]), fmaxf(sl0[2], sl0[3]));
        float m1 = fmaxf(fmaxf(sl1[0], sl1[1]), fmaxf(sl1[2], sl1[3]));
        float m2 = fmaxf(fmaxf(sl2[0], sl2[1]), fmaxf(sl2[2], sl2[3]));
        float m3 = fmaxf(fmaxf(sl3[0], sl3[1]), fmaxf(sl3[2], sl3[3]));
        #pragma unroll
        for (int off = 8; off <= 32; off <<= 1) {
            m0 = fmaxf(m0, __shfl_xor(m0, off));
            m1 = fmaxf(m1, __shfl_xor(m1, off));
            m2 = fmaxf(m2, __shfl_xor(m2, off));
            m3 = fmaxf(m3, __shfl_xor(m3, off));
        }
        float l0 = 0.f, l1 = 0.f, l2 = 0.f, l3 = 0.f;
        #pragma unroll
        for (int tg = 0; tg < 4; ++tg) {
            ps0[tg] = __expf(sl0[tg] - m0); l0 += ps0[tg];
            ps1[tg] = __expf(sl1[tg] - m1); l1 += ps1[tg];
            ps2[tg] = __expf(sl2[tg] - m2); l2 += ps2[tg];
            ps3[tg] = __expf(sl3[tg] - m3); l3 += ps3[tg];
        }
        // sum butterfly over strides 8,16,32: each of the 32 tokens counted once
        // (the 4 slots are distinct tokens; lanes differing in bits 3-5 hold the
        //  other 8 tokens per slot; oct-duplicate lanes are never combined)
        #pragma unroll
        for (int off = 8; off <= 32; off <<= 1) {
            l0 += __shfl_xor(l0, off);
            l1 += __shfl_xor(l1, off);
            l2 += __shfl_xor(l2, off);
            l3 += __shfl_xor(l3, off);
        }
        if (lane == 0) {
            mw[w][0] = m0; mw[w][1] = m1; mw[w][2] = m2; mw[w][3] = m3;
            lw[w][0] = l0; lw[w][1] = l1; lw[w][2] = l2; lw[w][3] = l3;
        }
    }

    // ---- PV (line-clean float2 rows; p broadcast from slot lanes) ----
    {
        const int t0 = w * 32;
        const float* vb0 = v_cache + (size_t)blk0 * (BLK_SZ * N_KV * HEAD_DIM)
                         + (size_t)h * HEAD_DIM + lane * 2;
        const float* vb1 = v_cache + (size_t)blk1 * (BLK_SZ * N_KV * HEAD_DIM)
                         + (size_t)h * HEAD_DIM + lane * 2;
        const float* vnewp = vsec + lane * 2;
        float2 a0 = {0,0}, a1 = {0,0}, a2 = {0,0}, a3 = {0,0};
        #pragma unroll
        for (int tb = 0; tb < 32; tb += 8) {
            float2 vv[8];
            #pragma unroll
            for (int u = 0; u < 8; ++u) {
                const int tt = tb + u;                     // 0..31 compile-time
                const float* vp = (c * CHUNK + t0 + tt == pos) ? vnewp
                    : ((tt < 16 ? vb0 : vb1) + (size_t)(tt & 15) * (N_KV * HEAD_DIM));
                vv[u] = *(const float2*)vp;
            }
            #pragma unroll
            for (int u = 0; u < 8; ++u) {
                const int tt = tb + u;
                const int src = 8 * (tt & 7);              // lane holding slot tt>>3
                const float q0 = __shfl(ps0[tt >> 3], src);
                const float q1 = __shfl(ps1[tt >> 3], src);
                const float q2 = __shfl(ps2[tt >> 3], src);
                const float q3 = __shfl(ps3[tt >> 3], src);
                a0.x = fmaf(q0, vv[u].x, a0.x); a0.y = fmaf(q0, vv[u].y, a0.y);
                a1.x = fmaf(q1, vv[u].x, a1.x); a1.y = fmaf(q1, vv[u].y, a1.y);
                a2.x = fmaf(q2, vv[u].x, a2.x); a2.y = fmaf(q2, vv[u].y, a2.y);
                a3.x = fmaf(q3, vv[u].x, a3.x); a3.y = fmaf(q3, vv[u].y, a3.y);
            }
        }
        *(float2*)(&red[w][0][lane * 2]) = a0;
        *(float2*)(&red[w][1][lane * 2]) = a1;
        *(float2*)(&red[w][2][lane * 2]) = a2;
        *(float2*)(&red[w][3][lane * 2]) = a3;
    }
    __syncthreads();

    {   // weighted cross-wave combine: 256 thr x float2 = 4 heads x 128 dims
        const int g = tid >> 6, d = (tid & 63) * 2;
        const float m0 = mw[0][g], m1 = mw[1][g], m2 = mw[2][g], m3 = mw[3][g];
        float M = fmaxf(fmaxf(m0, m1), fmaxf(m2, m3));
        const float e0 = __expf(m0 - M), e1 = __expf(m1 - M);
        const float e2 = __expf(m2 - M), e3 = __expf(m3 - M);
        float ox = red[0][g][d]   * e0 + red[1][g][d]   * e1
                 + red[2][g][d]   * e2 + red[3][g][d]   * e3;
        float oy = red[0][g][d+1] * e0 + red[1][g][d+1] * e1
                 + red[2][g][d+1] * e2 + red[3][g][d+1] * e3;
        size_t ob = (((size_t)sh * NCHUNK + c) * GROUP + g) * HEAD_DIM + d;
        *(float2*)(pacc + ob) = make_float2(ox, oy);
        if ((tid & 63) == 0) {
            const float L = lw[0][g] * e0 + lw[1][g] * e1 + lw[2][g] * e2 + lw[3][g] * e3;
            size_t ib = (((size_t)sh * NCHUNK + c) * GROUP + g) * 2;
            pml[ib] = M; pml[ib + 1] = L;
        }
    }
}

// ---------------- combine chunk partials; emit bf16 for the O-GEMM ----------------
__global__ __launch_bounds__(256)
void attn_reduce(const float* __restrict__ pacc, const float* __restrict__ pml,
                 const int* __restrict__ context_lens, unsigned short* __restrict__ outbf) {
    const int sh = blockIdx.x;
    const int s  = sh >> 3;
    const int h  = sh & 7;
    const int g    = threadIdx.x >> 6;
    const int lane = threadIdx.x & 63;
    const int ctx = context_lens[s];
    const int nc  = (ctx + CHUNK - 1) / CHUNK;

    float M = -1e30f;
    for (int cc = 0; cc < nc; ++cc)
        M = fmaxf(M, pml[(((size_t)sh * NCHUNK + cc) * GROUP + g) * 2]);
    float ox = 0.f, oy = 0.f, L = 0.f;
    for (int cc = 0; cc < nc; ++cc) {
        size_t idx = ((size_t)sh * NCHUNK + cc) * GROUP + g;
        float w = __expf(pml[idx*2] - M);
        L = fmaf(w, pml[idx*2+1], L);
        float2 pa = *(const float2*)(pacc + idx * HEAD_DIM + lane*2);
        ox = fmaf(w, pa.x, ox);
        oy = fmaf(w, pa.y, oy);
    }
    float inv = 1.0f / L;
    unsigned short* op = outbf + (size_t)s * Q_SIZE + (h * GROUP + g) * HEAD_DIM;
    ushort2 o2 = { (unsigned short)f2bf(ox * inv), (unsigned short)f2bf(oy * inv) };
    *(ushort2*)(op + lane * 2) = o2;
}

extern "C" void kernel_launch(void* const* d_in, const int* in_sizes, int n_in,
                              void* d_out, int out_size, void* d_ws, size_t ws_size,
                              hipStream_t stream) {
    const int*   positions    = (const int*)  d_in[0];
    const float* hidden       = (const float*)d_in[1];
    const float* k_cache      = (const float*)d_in[2];
    const float* v_cache      = (const float*)d_in[3];
    const int*   block_tables = (const int*)  d_in[4];
    const int*   context_lens = (const int*)  d_in[5];
    const float* W_qkv        = (const float*)d_in[6];
    const float* W_o          = (const float*)d_in[7];
    float* out = (float*)d_out;

    float* qkv_ws = (float*)d_ws;                                     // 393216 f
    unsigned short* hidden_bf = (unsigned short*)(qkv_ws + (size_t)NUM_SEQS * QKV_OUT);
    unsigned short* attn_bf   = hidden_bf + (size_t)NUM_SEQS * H_SIZE;
    float* scratch = (float*)(attn_bf + (size_t)NUM_SEQS * H_SIZE);    // reused region
    // scratch reuse: QKV partials (3.1M f) -> attn pacc/pml (4.3M f) -> O partials (2.1M f)
    float* pacc = scratch;                                             // 512*16*4*128 f
    float* pml  = scratch + (size_t)NUM_SEQS * N_KV * NCHUNK * GROUP * HEAD_DIM;

    // 0) X -> bf16 (once)
    cvt_bf16<<<(NUM_SEQS * H_SIZE / 4 + 255) / 256, 256, 0, stream>>>(
        hidden, hidden_bf, NUM_SEQS * H_SIZE / 4);
    // 1) QKV projection + fused reduce+RoPE
    gemm_mfma<<<dim3(QKV_OUT / 64, KSPLIT), 256, 0, stream>>>(hidden_bf, W_qkv, scratch, QKV_OUT);
    qkv_reduce_rope<<<dim3(NUM_SEQS, 14), 256, 0, stream>>>(scratch, qkv_ws, positions);
    // 2) flash-decode attention + combine
    attn_chunk<<<dim3(NUM_SEQS * N_KV, NCHUNK), 256, 0, stream>>>(
        qkv_ws, k_cache, v_cache, block_tables, context_lens, pacc, pml);
    attn_reduce<<<NUM_SEQS * N_KV, 256, 0, stream>>>(pacc, pml, context_lens, attn_bf);
    // 3) output projection + reduce
    gemm_mfma<<<dim3(Q_SIZE / 64, KSPLIT), 256, 0, stream>>>(attn_bf, W_o, scratch, Q_SIZE);
    reduce_ksplit<<<(NUM_SEQS * Q_SIZE + 255) / 256, 256, 0, stream>>>(scratch, out, NUM_SEQS * Q_SIZE);
}

// Round 13
// 194.867 us; speedup vs baseline: 1.1972x; 1.0143x over previous
//
#include <hip/hip_runtime.h>
#include <math.h>

#define H_SIZE   4096
#define N_HEADS  32
#define N_KV     8
#define HEAD_DIM 128
#define GROUP    4
#define Q_SIZE   4096
#define KV_SIZE  1024
#define QKV_OUT  6144          // Q_SIZE + 2*KV_SIZE
#define NUM_SEQS 64
#define MAX_CTX  2048
#define BLK_SZ   16
#define BLOCKS_PER_SEQ 128
#define ATT_SCALE 0.08838834764831845f   // 128^-0.5

#define CHUNK    128           // tokens per attn workgroup (4 waves x 32)
#define NCHUNK   16            // MAX_CTX / CHUNK
#define KSPLIT   8
#define KCHUNK   512           // H_SIZE / KSPLIT

typedef __attribute__((ext_vector_type(8))) short bf16x8;
typedef __attribute__((ext_vector_type(4))) float f32x4;

__device__ __forceinline__ short f2bf(float f) {
    return __builtin_bit_cast(short, (__bf16)f);   // lowers to v_cvt_pk_bf16_f32
}

__device__ __forceinline__ bf16x8 cvt8(float4 a, float4 b) {
    bf16x8 r;
    r[0]=f2bf(a.x); r[1]=f2bf(a.y); r[2]=f2bf(a.z); r[3]=f2bf(a.w);
    r[4]=f2bf(b.x); r[5]=f2bf(b.y); r[6]=f2bf(b.z); r[7]=f2bf(b.w);
    return r;
}

// ---------------- fp32 -> bf16 bulk convert (X operand, done once) ----------------
__global__ __launch_bounds__(256)
void cvt_bf16(const float* __restrict__ in, unsigned short* __restrict__ out, int n4) {
    int i = blockIdx.x * 256 + threadIdx.x;
    if (i >= n4) return;
    float4 v = *(const float4*)(in + (size_t)i * 4);
    ushort2 lo = { (unsigned short)f2bf(v.x), (unsigned short)f2bf(v.y) };
    ushort2 hi = { (unsigned short)f2bf(v.z), (unsigned short)f2bf(v.w) };
    *(ushort2*)(out + (size_t)i * 4)     = lo;
    *(ushort2*)(out + (size_t)i * 4 + 2) = hi;
}

// ---------------- MFMA GEMM: Yp[c][64][N] = A[64][4096] @ W[N][4096]^T ----------
__global__ __launch_bounds__(256)
void gemm_mfma(const unsigned short* __restrict__ A, const float* __restrict__ W,
               float* __restrict__ Yp, int N) {
    const int n0   = blockIdx.x * 64;
    const int k0   = blockIdx.y * KCHUNK;
    const int wave = threadIdx.x >> 6;
    const int lane = threadIdx.x & 63;
    const int ncol = n0 + wave * 16 + (lane & 15);
    const int klane = (lane >> 4) * 8;

    const float*          wrow = W + (size_t)ncol * H_SIZE + k0 + klane;
    const unsigned short* arow = A + (size_t)(lane & 15) * H_SIZE + k0 + klane;

    f32x4 acc[4] = {};
    for (int k = 0; k < KCHUNK; k += 32) {
        float4 wa = *(const float4*)(wrow + k);
        float4 wb = *(const float4*)(wrow + k + 4);
        bf16x8 bf = cvt8(wa, wb);
        #pragma unroll
        for (int m = 0; m < 4; ++m) {
            bf16x8 af = *(const bf16x8*)(const void*)(arow + (size_t)m * 16 * H_SIZE + k);
            acc[m] = __builtin_amdgcn_mfma_f32_16x16x32_bf16(af, bf, acc[m], 0, 0, 0);
        }
    }
    float* yp = Yp + (size_t)blockIdx.y * 64 * N;
    #pragma unroll
    for (int m = 0; m < 4; ++m)
        #pragma unroll
        for (int j = 0; j < 4; ++j)
            yp[(size_t)(m * 16 + (lane >> 4) * 4 + j) * N + ncol] = acc[m][j];
}

// ---------------- fused K-split reduce + RoPE for QKV ----------------
__global__ __launch_bounds__(256)
void qkv_reduce_rope(const float* __restrict__ Yp, float* __restrict__ qkv,
                     const int* __restrict__ positions) {
    const int s   = blockIdx.x;
    const int idx = blockIdx.y * 256 + threadIdx.x;
    const float pos = (float)positions[s];
    if (idx < 2560) {
        const int head = idx >> 6, d = idx & 63;
        const int j1 = (head < N_HEADS ? head * HEAD_DIM
                                       : Q_SIZE + (head - N_HEADS) * HEAD_DIM) + d;
        const int j2 = j1 + 64;
        float x1 = 0.f, x2 = 0.f;
        #pragma unroll
        for (int c = 0; c < KSPLIT; ++c) {
            x1 += Yp[((size_t)c * 64 + s) * QKV_OUT + j1];
            x2 += Yp[((size_t)c * 64 + s) * QKV_OUT + j2];
        }
        const float inv_freq = powf(10000.0f, -(float)d / 64.0f);
        const float ang = pos * inv_freq;
        const float cs = cosf(ang), sn = sinf(ang);
        qkv[(size_t)s * QKV_OUT + j1] = x1 * cs - x2 * sn;
        qkv[(size_t)s * QKV_OUT + j2] = x2 * cs + x1 * sn;
    } else if (idx < 3584) {
        const int j = Q_SIZE + KV_SIZE + (idx - 2560);
        float v = 0.f;
        #pragma unroll
        for (int c = 0; c < KSPLIT; ++c)
            v += Yp[((size_t)c * 64 + s) * QKV_OUT + j];
        qkv[(size_t)s * QKV_OUT + j] = v;
    }
}

__global__ __launch_bounds__(256)
void reduce_ksplit(const float* __restrict__ Yp, float* __restrict__ Y, int total) {
    int i = blockIdx.x * 256 + threadIdx.x;
    if (i >= total) return;
    float s = 0.f;
    #pragma unroll
    for (int c = 0; c < KSPLIT; ++c) s += Yp[(size_t)c * total + i];
    Y[i] = s;
}

// ---------------- Flash-decode attention: oct K loads + pair-hoisted ILP ----------------
// grid (NUM_SEQS*N_KV, NCHUNK); block 256 = 4 waves; chunk = 128 tokens.
// K phase: lane = (token j8 = lane>>3, oct = lane&7); token-groups processed in PAIRS
// with all 8 float4 loads issued before any FMA (2x in-flight bytes/wave vs R12),
// q LDS reads shared between the pair.
__global__ __launch_bounds__(256)
void attn_chunk(const float* __restrict__ qkv,
                const float* __restrict__ k_cache,
                const float* __restrict__ v_cache,
                const int*   __restrict__ block_tables,
                const int*   __restrict__ context_lens,
                float* __restrict__ pacc,   // [sh][c][g][128]
                float* __restrict__ pml) {  // [sh][c][g][2]
    const int sh = blockIdx.x;
    const int s  = sh >> 3;
    const int h  = sh & 7;
    const int c  = blockIdx.y;
    const int ctx = context_lens[s];
    if (c * CHUNK >= ctx) return;
    const int pos = ctx - 1;
    const int nv = min(CHUNK, ctx - c * CHUNK);

    __shared__ float qs[GROUP][HEAD_DIM];     // 2 KB
    __shared__ float red[4][GROUP][HEAD_DIM]; // 8 KB
    __shared__ float mw[4][GROUP];            // wave-local max
    __shared__ float lw[4][GROUP];            // wave-local sum

    const int tid  = threadIdx.x;
    const int w    = tid >> 6;
    const int lane = tid & 63;

    {   // q for this group's 4 heads: 512 contiguous floats, 256 thr x float2
        int i = tid * 2;
        const float* qsrc = qkv + (size_t)s * QKV_OUT + h * (GROUP * HEAD_DIM);
        *(float2*)(&qs[i >> 7][i & 127]) = *(const float2*)(qsrc + i);
    }
    __syncthreads();

    const int*   bt   = block_tables + s * BLOCKS_PER_SEQ;
    const float* ksec = qkv + (size_t)s * QKV_OUT + Q_SIZE + h * HEAD_DIM;
    const float* vsec = qkv + (size_t)s * QKV_OUT + Q_SIZE + KV_SIZE + h * HEAD_DIM;

    // this wave's two cache blocks (tokens w*32..+15 and +16..+31)
    const int blk0 = bt[c * (CHUNK / BLK_SZ) + w * 2];
    const int blk1 = bt[c * (CHUNK / BLK_SZ) + w * 2 + 1];

    // ---- K phase: 4 token-groups of 8, processed in pairs with hoisted loads ----
    float ps0[4], ps1[4], ps2[4], ps3[4];   // prob slots: token tg*8 + (lane>>3)
    {
        const int j8  = lane >> 3;
        const int oct = lane & 7;
        float sl0[4], sl1[4], sl2[4], sl3[4];
        #pragma unroll
        for (int tgp = 0; tgp < 2; ++tgp) {
            const int tgA = tgp * 2, tgB = tgp * 2 + 1;
            const int tkA = tgA * 8 + j8;
            const int tkB = tgB * 8 + j8;
            const int TA = c * CHUNK + w * 32 + tkA;
            const int TB = c * CHUNK + w * 32 + tkB;
            const float* kpA = (TA == pos) ? ksec
                : k_cache + ((size_t)(((tkA < 16) ? blk0 : blk1) * BLK_SZ + (tkA & 15)) * N_KV + h) * HEAD_DIM;
            const float* kpB = (TB == pos) ? ksec
                : k_cache + ((size_t)(((tkB < 16) ? blk0 : blk1) * BLK_SZ + (tkB & 15)) * N_KV + h) * HEAD_DIM;
            // issue all 8 line-clean loads before any FMA
            float4 ka[4], kb[4];
            #pragma unroll
            for (int i = 0; i < 4; ++i) {
                ka[i] = *(const float4*)(kpA + i * 32 + oct * 4);
                kb[i] = *(const float4*)(kpB + i * 32 + oct * 4);
            }
            float dA0 = 0.f, dA1 = 0.f, dA2 = 0.f, dA3 = 0.f;
            float dB0 = 0.f, dB1 = 0.f, dB2 = 0.f, dB3 = 0.f;
            #pragma unroll
            for (int i = 0; i < 4; ++i) {
                const int o = i * 32 + oct * 4;
                const float4 x0 = *(const float4*)(&qs[0][o]);
                const float4 x1 = *(const float4*)(&qs[1][o]);
                const float4 x2 = *(const float4*)(&qs[2][o]);
                const float4 x3 = *(const float4*)(&qs[3][o]);
                const float4 A = ka[i], B = kb[i];
                dA0 = fmaf(A.x,x0.x, fmaf(A.y,x0.y, fmaf(A.z,x0.z, fmaf(A.w,x0.w, dA0))));
                dA1 = fmaf(A.x,x1.x, fmaf(A.y,x1.y, fmaf(A.z,x1.z, fmaf(A.w,x1.w, dA1))));
                dA2 = fmaf(A.x,x2.x, fmaf(A.y,x2.y, fmaf(A.z,x2.z, fmaf(A.w,x2.w, dA2))));
                dA3 = fmaf(A.x,x3.x, fmaf(A.y,x3.y, fmaf(A.z,x3.z, fmaf(A.w,x3.w, dA3))));
                dB0 = fmaf(B.x,x0.x, fmaf(B.y,x0.y, fmaf(B.z,x0.z, fmaf(B.w,x0.w, dB0))));
                dB1 = fmaf(B.x,x1.x, fmaf(B.y,x1.y, fmaf(B.z,x1.z, fmaf(B.w,x1.w, dB1))));
                dB2 = fmaf(B.x,x2.x, fmaf(B.y,x2.y, fmaf(B.z,x2.z, fmaf(B.w,x2.w, dB2))));
                dB3 = fmaf(B.x,x3.x, fmaf(B.y,x3.y, fmaf(B.z,x3.z, fmaf(B.w,x3.w, dB3))));
            }
            // reduce over the 8 octs (strides 1,2,4)
            #pragma unroll
            for (int off = 1; off <= 4; off <<= 1) {
                dA0 += __shfl_xor(dA0, off); dB0 += __shfl_xor(dB0, off);
                dA1 += __shfl_xor(dA1, off); dB1 += __shfl_xor(dB1, off);
                dA2 += __shfl_xor(dA2, off); dB2 += __shfl_xor(dB2, off);
                dA3 += __shfl_xor(dA3, off); dB3 += __shfl_xor(dB3, off);
            }
            const bool vA = (w * 32 + tkA) < nv;
            const bool vB = (w * 32 + tkB) < nv;
            sl0[tgA] = vA ? dA0 * ATT_SCALE : -1e30f;
            sl1[tgA] = vA ? dA1 * ATT_SCALE : -1e30f;
            sl2[tgA] = vA ? dA2 * ATT_SCALE : -1e30f;
            sl3[tgA] = vA ? dA3 * ATT_SCALE : -1e30f;
            sl0[tgB] = vB ? dB0 * ATT_SCALE : -1e30f;
            sl1[tgB] = vB ? dB1 * ATT_SCALE : -1e30f;
            sl2[tgB] = vB ? dB2 * ATT_SCALE : -1e30f;
            sl3[tgB] = vB ? dB3 * ATT_SCALE : -1e30f;
        }
        // wave max per head: 4 local slots + butterfly over strides 8,16,32
        float m0 = fmaxf(fmaxf(sl0[0], sl0[1]), fmaxf(sl0[2], sl0[3]));
        float m1 = fmaxf(fmaxf(sl1[0], sl1[1]), fmaxf(sl1[2], sl1[3]));
        float m2 = fmaxf(fmaxf(sl2[0], sl2[1]), fmaxf(sl2[2], sl2[3]));
        float m3 = fmaxf(fmaxf(sl3[0], sl3[1]), fmaxf(sl3[2], sl3[3]));
        #pragma unroll
        for (int off = 8; off <= 32; off <<= 1) {
            m0 = fmaxf(m0, __shfl_xor(m0, off));
            m1 = fmaxf(m1, __shfl_xor(m1, off));
            m2 = fmaxf(m2, __shfl_xor(m2, off));
            m3 = fmaxf(m3, __shfl_xor(m3, off));
        }
        float l0 = 0.f, l1 = 0.f, l2 = 0.f, l3 = 0.f;
        #pragma unroll
        for (int tg = 0; tg < 4; ++tg) {
            ps0[tg] = __expf(sl0[tg] - m0); l0 += ps0[tg];
            ps1[tg] = __expf(sl1[tg] - m1); l1 += ps1[tg];
            ps2[tg] = __expf(sl2[tg] - m2); l2 += ps2[tg];
            ps3[tg] = __expf(sl3[tg] - m3); l3 += ps3[tg];
        }
        // sum butterfly over strides 8,16,32: each of the 32 tokens counted once
        #pragma unroll
        for (int off = 8; off <= 32; off <<= 1) {
            l0 += __shfl_xor(l0, off);
            l1 += __shfl_xor(l1, off);
            l2 += __shfl_xor(l2, off);
            l3 += __shfl_xor(l3, off);
        }
        if (lane == 0) {
            mw[w][0] = m0; mw[w][1] = m1; mw[w][2] = m2; mw[w][3] = m3;
            lw[w][0] = l0; lw[w][1] = l1; lw[w][2] = l2; lw[w][3] = l3;
        }
    }

    // ---- PV (line-clean float2 rows; p broadcast from slot lanes) ----
    {
        const int t0 = w * 32;
        const float* vb0 = v_cache + (size_t)blk0 * (BLK_SZ * N_KV * HEAD_DIM)
                         + (size_t)h * HEAD_DIM + lane * 2;
        const float* vb1 = v_cache + (size_t)blk1 * (BLK_SZ * N_KV * HEAD_DIM)
                         + (size_t)h * HEAD_DIM + lane * 2;
        const float* vnewp = vsec + lane * 2;
        float2 a0 = {0,0}, a1 = {0,0}, a2 = {0,0}, a3 = {0,0};
        #pragma unroll
        for (int tb = 0; tb < 32; tb += 8) {
            float2 vv[8];
            #pragma unroll
            for (int u = 0; u < 8; ++u) {
                const int tt = tb + u;                     // 0..31 compile-time
                const float* vp = (c * CHUNK + t0 + tt == pos) ? vnewp
                    : ((tt < 16 ? vb0 : vb1) + (size_t)(tt & 15) * (N_KV * HEAD_DIM));
                vv[u] = *(const float2*)vp;
            }
            #pragma unroll
            for (int u = 0; u < 8; ++u) {
                const int tt = tb + u;
                const int src = 8 * (tt & 7);              // lane holding slot tt>>3
                const float q0 = __shfl(ps0[tt >> 3], src);
                const float q1 = __shfl(ps1[tt >> 3], src);
                const float q2 = __shfl(ps2[tt >> 3], src);
                const float q3 = __shfl(ps3[tt >> 3], src);
                a0.x = fmaf(q0, vv[u].x, a0.x); a0.y = fmaf(q0, vv[u].y, a0.y);
                a1.x = fmaf(q1, vv[u].x, a1.x); a1.y = fmaf(q1, vv[u].y, a1.y);
                a2.x = fmaf(q2, vv[u].x, a2.x); a2.y = fmaf(q2, vv[u].y, a2.y);
                a3.x = fmaf(q3, vv[u].x, a3.x); a3.y = fmaf(q3, vv[u].y, a3.y);
            }
        }
        *(float2*)(&red[w][0][lane * 2]) = a0;
        *(float2*)(&red[w][1][lane * 2]) = a1;
        *(float2*)(&red[w][2][lane * 2]) = a2;
        *(float2*)(&red[w][3][lane * 2]) = a3;
    }
    __syncthreads();

    {   // weighted cross-wave combine: 256 thr x float2 = 4 heads x 128 dims
        const int g = tid >> 6, d = (tid & 63) * 2;
        const float m0 = mw[0][g], m1 = mw[1][g], m2 = mw[2][g], m3 = mw[3][g];
        float M = fmaxf(fmaxf(m0, m1), fmaxf(m2, m3));
        const float e0 = __expf(m0 - M), e1 = __expf(m1 - M);
        const float e2 = __expf(m2 - M), e3 = __expf(m3 - M);
        float ox = red[0][g][d]   * e0 + red[1][g][d]   * e1
                 + red[2][g][d]   * e2 + red[3][g][d]   * e3;
        float oy = red[0][g][d+1] * e0 + red[1][g][d+1] * e1
                 + red[2][g][d+1] * e2 + red[3][g][d+1] * e3;
        size_t ob = (((size_t)sh * NCHUNK + c) * GROUP + g) * HEAD_DIM + d;
        *(float2*)(pacc + ob) = make_float2(ox, oy);
        if ((tid & 63) == 0) {
            const float L = lw[0][g] * e0 + lw[1][g] * e1 + lw[2][g] * e2 + lw[3][g] * e3;
            size_t ib = (((size_t)sh * NCHUNK + c) * GROUP + g) * 2;
            pml[ib] = M; pml[ib + 1] = L;
        }
    }
}

// ---------------- combine chunk partials; emit bf16 for the O-GEMM ----------------
__global__ __launch_bounds__(256)
void attn_reduce(const float* __restrict__ pacc, const float* __restrict__ pml,
                 const int* __restrict__ context_lens, unsigned short* __restrict__ outbf) {
    const int sh = blockIdx.x;
    const int s  = sh >> 3;
    const int h  = sh & 7;
    const int g    = threadIdx.x >> 6;
    const int lane = threadIdx.x & 63;
    const int ctx = context_lens[s];
    const int nc  = (ctx + CHUNK - 1) / CHUNK;

    float M = -1e30f;
    for (int cc = 0; cc < nc; ++cc)
        M = fmaxf(M, pml[(((size_t)sh * NCHUNK + cc) * GROUP + g) * 2]);
    float ox = 0.f, oy = 0.f, L = 0.f;
    for (int cc = 0; cc < nc; ++cc) {
        size_t idx = ((size_t)sh * NCHUNK + cc) * GROUP + g;
        float w = __expf(pml[idx*2] - M);
        L = fmaf(w, pml[idx*2+1], L);
        float2 pa = *(const float2*)(pacc + idx * HEAD_DIM + lane*2);
        ox = fmaf(w, pa.x, ox);
        oy = fmaf(w, pa.y, oy);
    }
    float inv = 1.0f / L;
    unsigned short* op = outbf + (size_t)s * Q_SIZE + (h * GROUP + g) * HEAD_DIM;
    ushort2 o2 = { (unsigned short)f2bf(ox * inv), (unsigned short)f2bf(oy * inv) };
    *(ushort2*)(op + lane * 2) = o2;
}

extern "C" void kernel_launch(void* const* d_in, const int* in_sizes, int n_in,
                              void* d_out, int out_size, void* d_ws, size_t ws_size,
                              hipStream_t stream) {
    const int*   positions    = (const int*)  d_in[0];
    const float* hidden       = (const float*)d_in[1];
    const float* k_cache      = (const float*)d_in[2];
    const float* v_cache      = (const float*)d_in[3];
    const int*   block_tables = (const int*)  d_in[4];
    const int*   context_lens = (const int*)  d_in[5];
    const float* W_qkv        = (const float*)d_in[6];
    const float* W_o          = (const float*)d_in[7];
    float* out = (float*)d_out;

    float* qkv_ws = (float*)d_ws;                                     // 393216 f
    unsigned short* hidden_bf = (unsigned short*)(qkv_ws + (size_t)NUM_SEQS * QKV_OUT);
    unsigned short* attn_bf   = hidden_bf + (size_t)NUM_SEQS * H_SIZE;
    float* scratch = (float*)(attn_bf + (size_t)NUM_SEQS * H_SIZE);    // reused region
    // scratch reuse: QKV partials (3.1M f) -> attn pacc/pml (4.3M f) -> O partials (2.1M f)
    float* pacc = scratch;                                             // 512*16*4*128 f
    float* pml  = scratch + (size_t)NUM_SEQS * N_KV * NCHUNK * GROUP * HEAD_DIM;

    // 0) X -> bf16 (once)
    cvt_bf16<<<(NUM_SEQS * H_SIZE / 4 + 255) / 256, 256, 0, stream>>>(
        hidden, hidden_bf, NUM_SEQS * H_SIZE / 4);
    // 1) QKV projection + fused reduce+RoPE
    gemm_mfma<<<dim3(QKV_OUT / 64, KSPLIT), 256, 0, stream>>>(hidden_bf, W_qkv, scratch, QKV_OUT);
    qkv_reduce_rope<<<dim3(NUM_SEQS, 14), 256, 0, stream>>>(scratch, qkv_ws, positions);
    // 2) flash-decode attention + combine
    attn_chunk<<<dim3(NUM_SEQS * N_KV, NCHUNK), 256, 0, stream>>>(
        qkv_ws, k_cache, v_cache, block_tables, context_lens, pacc, pml);
    attn_reduce<<<NUM_SEQS * N_KV, 256, 0, stream>>>(pacc, pml, context_lens, attn_bf);
    // 3) output projection + reduce
    gemm_mfma<<<dim3(Q_SIZE / 64, KSPLIT), 256, 0, stream>>>(attn_bf, W_o, scratch, Q_SIZE);
    reduce_ksplit<<<(NUM_SEQS * Q_SIZE + 255) / 256, 256, 0, stream>>>(scratch, out, NUM_SEQS * Q_SIZE);
}